// Round 14
// baseline (599.538 us; speedup 1.0000x reference)
//
#include <hip/hip_runtime.h>
#include <hip/hip_bf16.h>
#include <math.h>

// ---------------------------------------------------------------------------
// GCN: 3x GCNConv(128->128) + fused (Wp1@Wp2) head + log_softmax.
// Round 25: sanitized slab retry. R23/R24 (identical source) both died with
// "container failed twice"; only novel toolchain feature vs all passing
// rounds was __builtin_nontemporal_load/store -> removed (plain loads).
// Everything else byte-identical to R24.
// XCD-sliced column-slab aggregation: agg's 2.8 TB/s was the L3 random-row
// service rate for a 25.6MB working set fitting NO single 4MB L2. Split
// D=128 into 8 slabs x 16 cols (3.2MB):
//  - hidden-state buffers slab-major: elem(s,node,c) at ((s*N+node)*16+c).
//  - gather_slab: EXACTLY 2048 co-resident grid-stride blocks;
//    slab = blockIdx&7 == XCD id under round-robin -> per-XCD L2-resident
//    slab; neighbor-row reads (32B) become L2 hits.
//  - gemm_slab / head_slab: dense MFMA, slab-major A-frags (16B aligned).
// Diagnostic: gather_slab FETCH ~60-90MB => win; ~190MB => mapping failed
// (revert to R9's 370us). 3rd container failure => slab structure implicated,
// revert + declare.
// ---------------------------------------------------------------------------

#define DH 128     // feature dim (D == H == 128)
#define NC 40      // classes
#define BN 128     // nodes per bucket
#define MAXNB 1024 // max buckets (N <= 131072)
#define CAP 2560   // edge capacity per bucket (mean 2048, +11 sigma)
#define CH 4096    // edges per scatter block
#define NPREP (3 * DH * DH + 48 * DH + 48)

typedef __attribute__((ext_vector_type(8))) short bf16x8;
typedef __attribute__((ext_vector_type(4))) float f32x4;

__device__ __forceinline__ unsigned short f2bf(float f) {
    unsigned u = __float_as_uint(f);
    unsigned r = (u + 0x7fffu + ((u >> 16) & 1u)) >> 16;   // RNE
    return (unsigned short)r;
}
__device__ __forceinline__ unsigned pack2(float lo, float hi) {
    return (unsigned)f2bf(lo) | ((unsigned)f2bf(hi) << 16);
}

// ---------------- E-pass 1 + weight prep (fused grid) -----------------------

__global__ __launch_bounds__(256) void bucket_scatter_prep(
        const int* __restrict__ src, const int* __restrict__ dst, int E,
        unsigned* __restrict__ bpos, unsigned* __restrict__ ebuf,
        const float* __restrict__ W1, const float* __restrict__ W2,
        const float* __restrict__ W3, const float* __restrict__ Wp1,
        const float* __restrict__ bp1, const float* __restrict__ Wp2,
        const float* __restrict__ bp2, unsigned short* __restrict__ Wt,
        unsigned short* __restrict__ Wft, float* __restrict__ bfh, int gC) {
    __shared__ unsigned hist[MAXNB];
    __shared__ unsigned gbase[MAXNB];
    __shared__ unsigned lim[MAXNB];
    __shared__ unsigned cur[MAXNB];
    const int tid = threadIdx.x;

    if (blockIdx.x >= gC) {               // ---- weight-prep tail blocks ----
        int id = (blockIdx.x - gC) * 256 + tid;
        if (id < 3 * DH * DH) {
            int l = id >> 14, r = id & (DH * DH - 1);
            int k = r >> 7, n = r & 127;
            const float* W = (l == 0) ? W1 : (l == 1) ? W2 : W3;
            Wt[l * DH * DH + n * DH + k] = f2bf(W[k * DH + n]);
        } else if (id < 3 * DH * DH + 48 * DH) {
            int o = id - 3 * DH * DH;
            int c = o >> 7, k = o & 127;
            float acc = 0.f;
            if (c < NC)
                for (int j = 0; j < DH; ++j) acc += Wp1[k * DH + j] * Wp2[j * NC + c];
            Wft[c * DH + k] = f2bf(acc);
        } else if (id < NPREP) {
            int c = id - 3 * DH * DH - 48 * DH;
            float acc = 0.f;
            if (c < NC) {
                acc = bp2[c];
                for (int j = 0; j < DH; ++j) acc += bp1[j] * Wp2[j * NC + c];
            }
            bfh[c] = acc;
        }
        return;
    }

    const int e0 = blockIdx.x * CH;
    const int nE = min(CH, E - e0);
    const int nE4 = nE & ~3;

    for (int i = tid; i < MAXNB; i += 256) { hist[i] = 0; cur[i] = 0; }
    __syncthreads();
    for (int i = tid * 4; i < nE4; i += 1024) {
        int4 dv = *(const int4*)(dst + e0 + i);
        atomicAdd(&hist[(unsigned)dv.x >> 7], 1u);
        atomicAdd(&hist[(unsigned)dv.y >> 7], 1u);
        atomicAdd(&hist[(unsigned)dv.z >> 7], 1u);
        atomicAdd(&hist[(unsigned)dv.w >> 7], 1u);
    }
    for (int i = nE4 + tid; i < nE; i += 256)
        atomicAdd(&hist[(unsigned)dst[e0 + i] >> 7], 1u);
    __syncthreads();
    for (int i = tid; i < MAXNB; i += 256) {
        unsigned h = hist[i];
        if (h) {
            unsigned o = (unsigned)i * CAP + atomicAdd(&bpos[i], h);
            gbase[i] = o;
            lim[i] = min(o + h, (unsigned)(i + 1) * CAP);
        }
    }
    __syncthreads();
    for (int i = tid * 4; i < nE4; i += 1024) {
        int4 sv = *(const int4*)(src + e0 + i);
        int4 dv = *(const int4*)(dst + e0 + i);
        {
            unsigned b = (unsigned)dv.x >> 7;
            unsigned p = gbase[b] + atomicAdd(&cur[b], 1u);
            if (p < lim[b]) ebuf[p] = ((unsigned)sv.x << 7) | ((unsigned)dv.x & 127u);
        }
        {
            unsigned b = (unsigned)dv.y >> 7;
            unsigned p = gbase[b] + atomicAdd(&cur[b], 1u);
            if (p < lim[b]) ebuf[p] = ((unsigned)sv.y << 7) | ((unsigned)dv.y & 127u);
        }
        {
            unsigned b = (unsigned)dv.z >> 7;
            unsigned p = gbase[b] + atomicAdd(&cur[b], 1u);
            if (p < lim[b]) ebuf[p] = ((unsigned)sv.z << 7) | ((unsigned)dv.z & 127u);
        }
        {
            unsigned b = (unsigned)dv.w >> 7;
            unsigned p = gbase[b] + atomicAdd(&cur[b], 1u);
            if (p < lim[b]) ebuf[p] = ((unsigned)sv.w << 7) | ((unsigned)dv.w & 127u);
        }
    }
    for (int i = nE4 + tid; i < nE; i += 256) {
        int s = src[e0 + i];
        int d = dst[e0 + i];
        unsigned b = (unsigned)d >> 7;
        unsigned p = gbase[b] + atomicAdd(&cur[b], 1u);
        if (p < lim[b]) ebuf[p] = ((unsigned)s << 7) | ((unsigned)d & 127u);
    }
}

// ---------------- E-pass 2: degree + nrm + dh + grouped CSR (merged) --------

__global__ __launch_bounds__(256) void bucket_degfill(const unsigned* __restrict__ ebuf,
                                                      const unsigned* __restrict__ bpos,
                                                      unsigned* __restrict__ cnt,
                                                      float* __restrict__ nrm,
                                                      unsigned* __restrict__ offN,
                                                      unsigned* __restrict__ dh,
                                                      int* __restrict__ csr, int N) {
    __shared__ unsigned h[BN], lb[BN], cur[BN];
    __shared__ int lcsr[CAP];
    __shared__ unsigned dhh[256];
    __shared__ unsigned tot;

    int b = blockIdx.x, tid = threadIdx.x;
    unsigned ebase = (unsigned)b * CAP;
    unsigned used = min(bpos[b], (unsigned)CAP);
    unsigned used4 = used & ~3u;

    if (tid < BN) { h[tid] = 0; cur[tid] = 0; }
    dhh[tid] = 0;
    if (tid == 0) tot = 0;
    __syncthreads();

    for (unsigned i = tid * 4; i < used4; i += 1024) {
        uint4 v = *(const uint4*)(ebuf + ebase + i);
        atomicAdd(&h[v.x & 127u], 1u);
        atomicAdd(&h[v.y & 127u], 1u);
        atomicAdd(&h[v.z & 127u], 1u);
        atomicAdd(&h[v.w & 127u], 1u);
    }
    for (unsigned i = used4 + tid; i < used; i += 256)
        atomicAdd(&h[ebuf[ebase + i] & 127u], 1u);
    __syncthreads();

    if (tid < BN) {
        unsigned m = h[tid];
        lb[tid] = m ? atomicAdd(&tot, m) : 0u;
    }
    __syncthreads();

    for (unsigned i = tid * 4; i < used4; i += 1024) {
        uint4 v = *(const uint4*)(ebuf + ebase + i);
        {
            unsigned nl = v.x & 127u;
            unsigned r = atomicAdd(&cur[nl], 1u);
            lcsr[lb[nl] + r] = (int)(v.x >> 7);
        }
        {
            unsigned nl = v.y & 127u;
            unsigned r = atomicAdd(&cur[nl], 1u);
            lcsr[lb[nl] + r] = (int)(v.y >> 7);
        }
        {
            unsigned nl = v.z & 127u;
            unsigned r = atomicAdd(&cur[nl], 1u);
            lcsr[lb[nl] + r] = (int)(v.z >> 7);
        }
        {
            unsigned nl = v.w & 127u;
            unsigned r = atomicAdd(&cur[nl], 1u);
            lcsr[lb[nl] + r] = (int)(v.w >> 7);
        }
    }
    for (unsigned i = used4 + tid; i < used; i += 256) {
        unsigned v = ebuf[ebase + i];
        unsigned nl = v & 127u;
        unsigned r = atomicAdd(&cur[nl], 1u);
        lcsr[lb[nl] + r] = (int)(v >> 7);
    }

    if (tid < BN) {
        int node = b * BN + tid;
        if (node < N) {
            unsigned m = h[tid];
            cnt[node] = m;
            nrm[node] = rsqrtf((float)m + 1.0f);
            offN[node] = ebase + lb[tid];
            atomicAdd(&dhh[min(m, 255u)], 1u);
        }
    }
    __syncthreads();

    for (unsigned i = tid * 4; i < used4; i += 1024)
        *(int4*)(csr + ebase + i) = *(const int4*)&lcsr[i];
    for (unsigned i = used4 + tid; i < used; i += 256)
        csr[ebase + i] = lcsr[i];
    if (dhh[tid]) atomicAdd(&dh[tid], dhh[tid]);
}

// ---------------- fused: layer-1 MFMA GEMM || deg_scatter (perm build) ------
// GEMM writes SLAB-MAJOR: elem(s=ct, node=r, c=m) at ((ct*N + r)*16 + m).

__global__ __launch_bounds__(256) void degscat_gemm(
        const unsigned* __restrict__ cnt, int N,
        const unsigned* __restrict__ dh, unsigned* __restrict__ binpos,
        const unsigned* __restrict__ offN, int* __restrict__ perm,
        unsigned* __restrict__ pd2,
        const float* __restrict__ X, const unsigned short* __restrict__ Wt,
        const float* __restrict__ nrm, unsigned short* __restrict__ outb,
        int gG) {
    __shared__ unsigned hh[256], base[256], cur[256], sdh[256], sns[256];
    const int tid = threadIdx.x;

    if (blockIdx.x >= (unsigned)gG) {     // ---- perm build (tail blocks) ----
        int t = tid;
        hh[t] = 0; cur[t] = 0; sdh[t] = dh[t];
        __syncthreads();
        unsigned ns = 0;
        for (int d = t + 1; d < 256; ++d) ns += sdh[d];
        sns[t] = ns;
        int i = (blockIdx.x - gG) * 256 + t;
        unsigned d = 0;
        if (i < N) { d = min(cnt[i], 255u); atomicAdd(&hh[d], 1u); }
        __syncthreads();
        if (hh[t]) base[t] = sns[t] + atomicAdd(&binpos[t], hh[t]);
        __syncthreads();
        if (i < N) {
            unsigned r = atomicAdd(&cur[d], 1u);
            unsigned idx = base[d] + r;
            perm[idx] = i;
            pd2[idx] = (offN[i] << 9) | min(cnt[i], 511u);
        }
        return;
    }

    // ---- GEMM ----
    const int wave = tid >> 6;
    const int lane = tid & 63;
    const int m = lane & 15;
    const int quad = lane >> 4;
    const int rbase = blockIdx.x * 64 + wave * 16;

    union U8 { bf16x8 v; unsigned u[4]; };

    f32x4 acc[8];
#pragma unroll
    for (int ct = 0; ct < 8; ++ct) acc[ct] = (f32x4){0.f, 0.f, 0.f, 0.f};

#pragma unroll
    for (int kt = 0; kt < 4; ++kt) {
        const int kof = kt * 32 + quad * 8;
        int r = rbase + m;
        r = (r < N) ? r : (N - 1);
        const float* p = X + (size_t)r * DH + kof;
        float4 u0 = *(const float4*)p;
        float4 u1 = *(const float4*)(p + 4);
        U8 t;
        t.u[0] = pack2(u0.x, u0.y);
        t.u[1] = pack2(u0.z, u0.w);
        t.u[2] = pack2(u1.x, u1.y);
        t.u[3] = pack2(u1.z, u1.w);
        bf16x8 a = t.v;
        bf16x8 b[8];
#pragma unroll
        for (int ct = 0; ct < 8; ++ct)
            b[ct] = *(const bf16x8*)(Wt + (ct * 16 + m) * DH + kof);
#pragma unroll
        for (int ct = 0; ct < 8; ++ct)
            acc[ct] = __builtin_amdgcn_mfma_f32_16x16x32_bf16(a, b[ct], acc[ct], 0, 0, 0);
    }

#pragma unroll
    for (int reg = 0; reg < 4; ++reg) {
        int r = rbase + quad * 4 + reg;
        if (r < N) {
            float s = nrm[r];
#pragma unroll
            for (int ct = 0; ct < 8; ++ct)
                outb[((size_t)ct * N + r) * 16 + m] = f2bf(acc[ct][reg] * s);
        }
    }
}

// ---------------- gather_slab: per-XCD L2-resident aggregation --------------
// slab = blockIdx&7 (XCD round-robin); EXACTLY 2048 blocks, grid-stride over
// chunks -> all blocks co-resident, no slab drift. 8-lane groups, 4B/lane
// (32B row-slab reads -> L2 hits). Output:
// Hs[(s*N+node)*8 + l2] = relu(acc*nrm + bias) packed bf16x2.

__global__ __launch_bounds__(256) void gather_slab(
        const unsigned* __restrict__ Abs, const int* __restrict__ csr,
        const unsigned* __restrict__ pd2, const int* __restrict__ perm,
        const float* __restrict__ bias, unsigned* __restrict__ Hs,
        int N, int nchunk) {
    const int tid = threadIdx.x;
    const int slab = blockIdx.x & 7;
    const int g = tid >> 3;                       // 32 groups/block
    const int l2 = tid & 7;                       // lane in group
    const int sb = ((tid & 63) >> 3) << 3;        // group base within wave

    const size_t sbase = (size_t)slab * (unsigned)N;
    const float2 bv = *(const float2*)(bias + slab * 16 + l2 * 2);

    for (int chunk = blockIdx.x >> 3; chunk < nchunk; chunk += 256) {
        const int pbase = chunk * 256 + g * 8;
#pragma unroll 1
        for (int t = 0; t < 8; ++t) {
            const int idx = pbase + t;
            if (idx >= N) break;
            const unsigned pd = pd2[idx];
            const unsigned o = pd >> 9;
            const unsigned d = pd & 511u;
            const int node = perm[idx];

            int i0 = 0, i1 = 0, i2 = 0, i3 = 0;
            if ((unsigned)l2 < d)        i0 = csr[o + l2];
            if ((unsigned)(8 + l2) < d)  i1 = csr[o + 8 + l2];
            if ((unsigned)(16 + l2) < d) i2 = csr[o + 16 + l2];
            if ((unsigned)(24 + l2) < d) i3 = csr[o + 24 + l2];

            unsigned sv = Abs[(sbase + (unsigned)node) * 8 + l2];
            float a0 = __uint_as_float(sv << 16);
            float a1 = __uint_as_float(sv & 0xffff0000u);

            const unsigned dl = min(d, 32u);
            unsigned e = 0;
            for (; e + 4 <= dl; e += 4) {
                int rsel = (e < 8) ? i0 : (e < 16) ? i1 : (e < 24) ? i2 : i3;
                int bb = sb + (int)(e & 7u);
                int s0 = __shfl(rsel, bb + 0);
                int s1 = __shfl(rsel, bb + 1);
                int s2 = __shfl(rsel, bb + 2);
                int s3 = __shfl(rsel, bb + 3);
                unsigned v0 = Abs[(sbase + (unsigned)s0) * 8 + l2];
                unsigned v1 = Abs[(sbase + (unsigned)s1) * 8 + l2];
                unsigned v2 = Abs[(sbase + (unsigned)s2) * 8 + l2];
                unsigned v3 = Abs[(sbase + (unsigned)s3) * 8 + l2];
                a0 += __uint_as_float(v0 << 16); a1 += __uint_as_float(v0 & 0xffff0000u);
                a0 += __uint_as_float(v1 << 16); a1 += __uint_as_float(v1 & 0xffff0000u);
                a0 += __uint_as_float(v2 << 16); a1 += __uint_as_float(v2 & 0xffff0000u);
                a0 += __uint_as_float(v3 << 16); a1 += __uint_as_float(v3 & 0xffff0000u);
            }
            for (; e < dl; ++e) {
                int rsel = (e < 8) ? i0 : (e < 16) ? i1 : (e < 24) ? i2 : i3;
                int s0 = __shfl(rsel, sb + (int)(e & 7u));
                unsigned v = Abs[(sbase + (unsigned)s0) * 8 + l2];
                a0 += __uint_as_float(v << 16); a1 += __uint_as_float(v & 0xffff0000u);
            }
            for (; e < d; ++e) {                  // d > 32 spill (P ~ 2e-4)
                int s0 = csr[o + e];
                unsigned v = Abs[(sbase + (unsigned)s0) * 8 + l2];
                a0 += __uint_as_float(v << 16); a1 += __uint_as_float(v & 0xffff0000u);
            }

            float nm = rsqrtf((float)d + 1.0f);
            Hs[(sbase + (unsigned)node) * 8 + l2] =
                pack2(fmaxf(a0 * nm + bv.x, 0.f), fmaxf(a1 * nm + bv.y, 0.f));
        }
    }
}

// ---------------- gemm_slab: dense MFMA, slab-major in/out ------------------

__global__ __launch_bounds__(256) void gemm_slab(
        const unsigned short* __restrict__ Hs,
        const unsigned short* __restrict__ Wt,
        const float* __restrict__ nrm,
        unsigned short* __restrict__ outb, int N) {
    const int tid = threadIdx.x;
    const int wave = tid >> 6;
    const int lane = tid & 63;
    const int m = lane & 15;
    const int quad = lane >> 4;
    const int rbase = blockIdx.x * 64 + wave * 16;

    f32x4 acc[8];
#pragma unroll
    for (int ct = 0; ct < 8; ++ct) acc[ct] = (f32x4){0.f, 0.f, 0.f, 0.f};

#pragma unroll
    for (int kt = 0; kt < 4; ++kt) {
        const int kof = kt * 32 + quad * 8;
        const int slab = kof >> 4;
        const int koff = kof & 15;
        int r = rbase + m;
        r = (r < N) ? r : (N - 1);
        bf16x8 a = *(const bf16x8*)(Hs + ((size_t)slab * N + r) * 16 + koff);
        bf16x8 b[8];
#pragma unroll
        for (int ct = 0; ct < 8; ++ct)
            b[ct] = *(const bf16x8*)(Wt + (ct * 16 + m) * DH + kof);
#pragma unroll
        for (int ct = 0; ct < 8; ++ct)
            acc[ct] = __builtin_amdgcn_mfma_f32_16x16x32_bf16(a, b[ct], acc[ct], 0, 0, 0);
    }

#pragma unroll
    for (int reg = 0; reg < 4; ++reg) {
        int r = rbase + quad * 4 + reg;
        if (r < N) {
            float s = nrm[r];
#pragma unroll
            for (int ct = 0; ct < 8; ++ct)
                outb[((size_t)ct * N + r) * 16 + m] = f2bf(acc[ct][reg] * s);
        }
    }
}

// ---------------- head_slab: head GEMM + log_softmax, slab-major in ---------

__global__ __launch_bounds__(256) void head_slab(
        const unsigned short* __restrict__ Hs,
        const unsigned short* __restrict__ Wft,
        const float* __restrict__ bfh,
        float* __restrict__ out, int N) {
    const int tid = threadIdx.x;
    const int wave = tid >> 6;
    const int lane = tid & 63;
    const int m = lane & 15;
    const int quad = lane >> 4;
    const int rbase = blockIdx.x * 64 + wave * 16;

    f32x4 acc[3];
#pragma unroll
    for (int ct = 0; ct < 3; ++ct) acc[ct] = (f32x4){0.f, 0.f, 0.f, 0.f};

#pragma unroll
    for (int kt = 0; kt < 4; ++kt) {
        const int kof = kt * 32 + quad * 8;
        const int slab = kof >> 4;
        const int koff = kof & 15;
        int r = rbase + m;
        r = (r < N) ? r : (N - 1);
        bf16x8 a = *(const bf16x8*)(Hs + ((size_t)slab * N + r) * 16 + koff);
#pragma unroll
        for (int ct = 0; ct < 3; ++ct) {
            bf16x8 b = *(const bf16x8*)(Wft + (ct * 16 + m) * DH + kof);
            acc[ct] = __builtin_amdgcn_mfma_f32_16x16x32_bf16(a, b, acc[ct], 0, 0, 0);
        }
    }

    float bias0 = bfh[m];
    float bias1 = bfh[16 + m];
    float bias2 = bfh[32 + m];

#pragma unroll
    for (int reg = 0; reg < 4; ++reg) {
        float v0 = acc[0][reg] + bias0;
        float v1 = acc[1][reg] + bias1;
        float v2 = (m < 8) ? (acc[2][reg] + bias2) : -1e30f;
        float mx = fmaxf(fmaxf(v0, v1), v2);
#pragma unroll
        for (int dlt = 1; dlt < 16; dlt <<= 1) mx = fmaxf(mx, __shfl_xor(mx, dlt));
        float s = __expf(v0 - mx) + __expf(v1 - mx) + ((m < 8) ? __expf(v2 - mx) : 0.f);
#pragma unroll
        for (int dlt = 1; dlt < 16; dlt <<= 1) s += __shfl_xor(s, dlt);
        float ls = mx + __logf(s);
        int r = rbase + quad * 4 + reg;
        if (r < N) {
            out[(size_t)r * NC + m] = v0 - ls;
            out[(size_t)r * NC + 16 + m] = v1 - ls;
            if (m < 8) out[(size_t)r * NC + 32 + m] = v2 - ls;
        }
    }
}

// ---------------------------------------------------------------------------

extern "C" void kernel_launch(void* const* d_in, const int* in_sizes, int n_in,
                              void* d_out, int out_size, void* d_ws, size_t ws_size,
                              hipStream_t stream) {
    const float* x   = (const float*)d_in[0];
    const int*   ei  = (const int*)d_in[1];
    const float* W1  = (const float*)d_in[2];
    const float* b1  = (const float*)d_in[3];
    const float* W2  = (const float*)d_in[4];
    const float* b2  = (const float*)d_in[5];
    const float* W3  = (const float*)d_in[6];
    const float* b3  = (const float*)d_in[7];
    const float* Wp1 = (const float*)d_in[8];
    const float* bp1 = (const float*)d_in[9];
    const float* Wp2 = (const float*)d_in[10];
    const float* bp2 = (const float*)d_in[11];
    float* out = (float*)d_out;

    const int N = in_sizes[0] / DH;
    const int E = in_sizes[1] / 2;
    const int* src = ei;
    const int* dst = ei + E;
    const int NB = (N + BN - 1) / BN;

    // workspace carve (all 16B aligned)
    char* w = (char*)d_ws;
    unsigned short* Ab  = (unsigned short*)w; w += (size_t)N * DH * 2;   // slab-major
    unsigned short* Bb  = (unsigned short*)w; w += (size_t)N * DH * 2;   // slab-major
    int*      csr    = (int*)w;      w += (size_t)NB * CAP * 4;
    unsigned* ebuf   = (unsigned*)w; w += (size_t)NB * CAP * 4;
    // ---- zeroed region (one memset): dh + binpos + bpos ----
    unsigned* dh     = (unsigned*)w; w += 256 * 4;
    unsigned* binpos = (unsigned*)w; w += 256 * 4;
    unsigned* bpos   = (unsigned*)w; w += MAXNB * 4;
    // ---- end zeroed region ----
    unsigned* cnt    = (unsigned*)w; w += (size_t)N * 4;
    float*    nrm    = (float*)w;    w += (size_t)N * 4;
    unsigned* offN   = (unsigned*)w; w += (size_t)N * 4;
    unsigned* pd2    = (unsigned*)w; w += (size_t)((N + 31) & ~31) * 4;
    int*      perm   = (int*)w;      w += (size_t)((N + 31) & ~31) * 4;
    unsigned short* Wt  = (unsigned short*)w; w += 3 * DH * DH * 2;
    unsigned short* Wft = (unsigned short*)w; w += 48 * DH * 2;
    float*    bfh    = (float*)w;    w += 64 * 4;

    const int gC = (E + CH - 1) / CH;
    const int gN = (N + 255) / 256;
    const int gP = (NPREP + 255) / 256;
    const int gG = (N + 63) / 64;
    const int nchunk = (N + 255) / 256;

    hipMemsetAsync(dh, 0, 256 * 4 + 256 * 4 + MAXNB * 4, stream);
    bucket_scatter_prep<<<gC + gP, 256, 0, stream>>>(src, dst, E, bpos, ebuf,
                                                     W1, W2, W3, Wp1, bp1, Wp2, bp2,
                                                     Wt, Wft, bfh, gC);
    bucket_degfill<<<NB, 256, 0, stream>>>(ebuf, bpos, cnt, nrm, offN, dh, csr, N);
    degscat_gemm<<<gG + gN, 256, 0, stream>>>(cnt, N, dh, binpos, offN, perm, pd2,
                                              x, Wt, nrm, Ab, gG);

    // layer 1 aggregate -> h1 ; layer 2 pre-product ; ...
    gather_slab<<<2048, 256, 0, stream>>>((const unsigned*)Ab, csr, pd2, perm, b1,
                                          (unsigned*)Bb, N, nchunk);
    gemm_slab<<<gG, 256, 0, stream>>>(Bb, Wt + DH * DH, nrm, Ab, N);
    gather_slab<<<2048, 256, 0, stream>>>((const unsigned*)Ab, csr, pd2, perm, b2,
                                          (unsigned*)Bb, N, nchunk);
    gemm_slab<<<gG, 256, 0, stream>>>(Bb, Wt + 2 * DH * DH, nrm, Ab, N);
    gather_slab<<<2048, 256, 0, stream>>>((const unsigned*)Ab, csr, pd2, perm, b3,
                                          (unsigned*)Bb, N, nchunk);
    head_slab<<<gG, 256, 0, stream>>>(Bb, Wft, bfh, out, N);
}